// Round 5
// baseline (376.240 us; speedup 1.0000x reference)
//
#include <hip/hip_runtime.h>
#include <stdint.h>

typedef __attribute__((ext_vector_type(4))) float f32x4;
typedef __attribute__((ext_vector_type(8))) __bf16 bf16x8;
typedef __attribute__((ext_vector_type(4))) __bf16 bf16x4;

#define NB 2
#define NS 2048
#define ND 2048
#define NH 16
#define NHD 128
#define NM (NB*NS)      // 4096 rows
#define NQKV (3*ND)     // 6144

__device__ __forceinline__ short f2bf(float f) {
  union { float f; uint32_t u; } c; c.f = f;
  uint32_t r = (c.u + 0x7FFFu + ((c.u >> 16) & 1u)) >> 16;
  return (short)r;
}

__device__ __forceinline__ void gl_lds16(const short* g, short* l) {
  __builtin_amdgcn_global_load_lds(
      (const __attribute__((address_space(1))) void*)g,
      (__attribute__((address_space(3))) void*)l, 16, 0, 0);
}

// ---------------- fp32 -> bf16 elementwise ----------------
__global__ __launch_bounds__(256) void cvt_bf16_kernel(const float* __restrict__ in,
                                                       short* __restrict__ out, int n4) {
  int i = blockIdx.x * 256 + threadIdx.x;
  if (i >= n4) return;
  float4 v = ((const float4*)in)[i];
  short4 o;
  o.x = f2bf(v.x); o.y = f2bf(v.y); o.z = f2bf(v.z); o.w = f2bf(v.w);
  ((short4*)out)[i] = o;
}

// ---------------- fp32 [rows][cols] -> bf16 [cols][rows] ----------------
__global__ __launch_bounds__(256) void transpose_cvt_kernel(const float* __restrict__ in,
                                                            short* __restrict__ out,
                                                            int rows, int cols) {
  __shared__ float tile[64][65];
  const int tx = threadIdx.x, ty = threadIdx.y;
  const int r0 = blockIdx.y * 64, c0 = blockIdx.x * 64;
  for (int i = ty; i < 64; i += 4)
    tile[i][tx] = in[(size_t)(r0 + i) * cols + c0 + tx];
  __syncthreads();
  for (int i = ty; i < 64; i += 4)
    out[(size_t)(c0 + i) * rows + r0 + tx] = f2bf(tile[tx][i]);
}

// ---------------- bf16 GEMM, 256x256 tile, BK=64, 8 waves, 4-phase + counted vmcnt ----
// C = A[M][K] * Bt[N][K]^T. LDS XOR-swizzled (T2), raw barriers + vmcnt(8) (T3/T4),
// setprio around MFMA clusters (T5), XCD-contiguous block remap (T1).
template<int EPI>
__global__ __launch_bounds__(512, 2) void gemm_kernel(
    const short* __restrict__ A, const short* __restrict__ Bt, int K, int N, int nbx,
    const float* __restrict__ bias,
    short* __restrict__ Qb, short* __restrict__ Kb, short* __restrict__ Vtb,
    const float* __restrict__ residual, float* __restrict__ out) {
  const int tid = threadIdx.x;
  const int wid = tid >> 6, l = tid & 63;
  const int l15 = l & 15, l4 = l >> 4;
  const int wr = wid >> 2, wc = wid & 3;

  // T1: XCD k gets a contiguous chunk of the (bx-fastest) tile space.
  const int NT = gridDim.x;
  const int flat = blockIdx.x;
  const int swz = (flat & 7) * (NT >> 3) + (flat >> 3);
  const int bx = swz % nbx, by = swz / nbx;
  const int rowBase = by * 256, colBase = bx * 256;

  __shared__ short As[2][256 * 64];   // 64 KB (2 buf)
  __shared__ short Bs[2][256 * 64];   // 64 KB

  f32x4 acc[8][4] = {};

  const int nk = K >> 6;
  // staging: inst i covers rows i*64..i*64+63; thread -> row = i*64 + wid*8 + (l>>3),
  // swizzled source col-element = ((l&7)^(l>>3))*8  (LDS dest linear, T2 rule #21)
  const int srow = wid * 8 + (l >> 3);
  const int scol = ((l & 7) ^ (l >> 3)) << 3;

#define GSTAGE(buf, kt0) do {                                              \
    const size_t kOff = (size_t)(kt0) * 64 + scol;                         \
    _Pragma("unroll")                                                      \
    for (int i_ = 0; i_ < 4; ++i_) {                                       \
      gl_lds16(A  + (size_t)(rowBase + i_ * 64 + srow) * K + kOff,         \
               &As[buf][i_ * 4096 + wid * 512]);                           \
      gl_lds16(Bt + (size_t)(colBase + i_ * 64 + srow) * K + kOff,         \
               &Bs[buf][i_ * 4096 + wid * 512]);                           \
    }                                                                      \
  } while (0)

  bf16x8 af[4][2], bfr[2][2];
  const int aXor = (l15 & 7) << 4;   // byte XOR, same involution as staging
  const int aColB = l4 * 16;

#define LDA(Ab, mh)                                                        \
  _Pragma("unroll")                                                        \
  for (int m_ = 0; m_ < 4; ++m_) {                                         \
    const int r_ = wr * 128 + (mh) * 64 + m_ * 16 + l15;                   \
    _Pragma("unroll")                                                      \
    for (int kk_ = 0; kk_ < 2; ++kk_)                                      \
      af[m_][kk_] = *(const bf16x8*)((Ab) + r_ * 128 + ((kk_ * 64 + aColB) ^ aXor)); \
  }
#define LDB(Bb, nh)                                                        \
  _Pragma("unroll")                                                        \
  for (int n_ = 0; n_ < 2; ++n_) {                                         \
    const int r_ = wc * 64 + (nh) * 32 + n_ * 16 + l15;                    \
    _Pragma("unroll")                                                      \
    for (int kk_ = 0; kk_ < 2; ++kk_)                                      \
      bfr[n_][kk_] = *(const bf16x8*)((Bb) + r_ * 128 + ((kk_ * 64 + aColB) ^ aXor)); \
  }
#define MMA(mh, nh)                                                        \
  asm volatile("s_waitcnt lgkmcnt(0)" ::: "memory");                       \
  __builtin_amdgcn_sched_barrier(0);                                       \
  __builtin_amdgcn_s_setprio(1);                                           \
  _Pragma("unroll")                                                        \
  for (int m_ = 0; m_ < 4; ++m_)                                           \
    _Pragma("unroll")                                                      \
    for (int n_ = 0; n_ < 2; ++n_)                                         \
      _Pragma("unroll")                                                    \
      for (int kk_ = 0; kk_ < 2; ++kk_)                                    \
        acc[(mh) * 4 + m_][(nh) * 2 + n_] = __builtin_amdgcn_mfma_f32_16x16x32_bf16( \
            af[m_][kk_], bfr[n_][kk_], acc[(mh) * 4 + m_][(nh) * 2 + n_], 0, 0, 0);  \
  __builtin_amdgcn_s_setprio(0);

  // prologue: prime both buffers; wait own tile-0 loads; barrier -> everyone's landed
  GSTAGE(0, 0);
  GSTAGE(1, 1);
  asm volatile("s_waitcnt vmcnt(8)" ::: "memory");
  __builtin_amdgcn_s_barrier();
  __builtin_amdgcn_sched_barrier(0);

  for (int kt = 0; kt < nk; ++kt) {
    const int cur = kt & 1;
    const char* Ab = (const char*)&As[cur][0];
    const char* Bb = (const char*)&Bs[cur][0];
    // 4 quadrant phases; A-frags reused across n-halves, B zig-zag reused across m-halves
    LDA(Ab, 0); LDB(Bb, 0); MMA(0, 0);
    LDB(Bb, 1);             MMA(0, 1);
    LDA(Ab, 1);             MMA(1, 1);
    LDB(Bb, 0);             MMA(1, 0);
    __builtin_amdgcn_sched_barrier(0);
    __builtin_amdgcn_s_barrier();          // all waves done reading buf[cur]
    __builtin_amdgcn_sched_barrier(0);
    if (kt + 2 < nk) {
      GSTAGE(cur, kt + 2);                 // refill just-released buffer
      asm volatile("s_waitcnt vmcnt(8)" ::: "memory");  // tile kt+1 landed; kt+2 in flight
    } else {
      asm volatile("s_waitcnt vmcnt(0)" ::: "memory");  // tail drain
    }
    __builtin_amdgcn_s_barrier();          // buf[cur^1] valid for everyone
    __builtin_amdgcn_sched_barrier(0);
  }
#undef GSTAGE
#undef LDA
#undef LDB
#undef MMA

#pragma unroll
  for (int m = 0; m < 8; ++m) {
#pragma unroll
    for (int n = 0; n < 4; ++n) {
#pragma unroll
      for (int r = 0; r < 4; ++r) {
        const int row = rowBase + wr * 128 + m * 16 + l4 * 4 + r;
        const int col = colBase + wc * 64 + n * 16 + l15;
        float v = acc[m][n][r] + bias[col];
        if (EPI == 0) {
          const int h = col / 384;
          const int sub = col - h * 384;
          const int t = sub >> 7, hd = sub & 127;
          const int bb = row >> 11, s = row & 2047;
          const size_t bh = (size_t)bb * NH + h;
          if (t == 0)      Qb[(bh * NS + s) * NHD + hd] = f2bf(v * 0.08838834764831845f);
          else if (t == 1) Kb[(bh * NS + s) * NHD + hd] = f2bf(v);
          else             Vtb[(bh * NHD + hd) * NS + s] = f2bf(v);
        } else {
          const size_t idx = (size_t)row * N + col;
          out[idx] = v + residual[idx];
        }
      }
    }
  }
}

// ---------------- flash attention v4: QBLK=32/wave, K in LDS (swizzled) ----------------
__global__ __launch_bounds__(256, 2) void attn_kernel(
    const short* __restrict__ Qb, const short* __restrict__ Kb,
    const short* __restrict__ Vtb, const float* __restrict__ alibi,
    const int* __restrict__ amask, short* __restrict__ Ob) {
  const int tid = threadIdx.x;
  const int w = tid >> 6, l = tid & 63;
  const int l15 = l & 15, l4 = l >> 4;
  const int flat = blockIdx.x;
  const int bh = flat & 31;
  const int y = (flat >> 5) & 7, z = flat >> 8;
  const int qt = z ? (15 - y) : y;
  const int bb = bh >> 4, h = bh & 15;
  const int q0 = qt * 128;
  const int qw = q0 + w * 32;
  const int NT = 2 * qt + 2;

  __shared__ float biasLds[NS];
  __shared__ short Ks[2][64 * 128];
  __shared__ short Plds[4][32 * 64];

  {
    const float* abase = alibi + (size_t)bh * NS;
    const int* mbase = amask + (size_t)bb * NS;
    for (int i = tid; i < NS; i += 256)
      biasLds[i] = mbase[i] ? abase[i] : -1e30f;
  }

  const short* kbase = Kb + (size_t)bh * NS * NHD;
  const short* vbase = Vtb + (size_t)bh * NHD * NS;

#define KSTAGE(buf, kt0) do {                                                  \
    _Pragma("unroll")                                                          \
    for (int i_ = 0; i_ < 4; ++i_) {                                           \
      const int Lb_ = w * 4096 + i_ * 1024 + l * 16;                           \
      const int row_ = Lb_ >> 8;                                               \
      const int X_ = (Lb_ & 255) ^ ((row_ & 7) << 4);                          \
      gl_lds16((const short*)((const char*)kbase + (size_t)((kt0) * 64 + row_) * 256 + X_), \
               (short*)((char*)&Ks[buf][0] + (w * 4096 + i_ * 1024)));         \
    }                                                                          \
  } while (0)

  const short* qp = Qb + ((size_t)bh * NS + qw + l15) * NHD + l4 * 8;
  bf16x8 qf[2][4];
#pragma unroll
  for (int c = 0; c < 2; ++c)
#pragma unroll
    for (int s = 0; s < 4; ++s)
      qf[c][s] = *(const bf16x8*)(qp + c * 16 * NHD + s * 32);

  f32x4 acc[2][8] = {};
  float mrun[2] = {-1e30f, -1e30f}, lrun[2] = {0.f, 0.f};

  short* myP = &Plds[w][0];
  const int pswzB = (l15 & 7) << 4;
  const int qg0 = qw + l15, qg1 = qw + 16 + l15;

  KSTAGE(0, 0);
  __syncthreads();
  int cur = 0;

  for (int t = 0; t < NT; ++t) {
    const int k0 = t << 6;
    if (t + 1 < NT) KSTAGE(cur ^ 1, t + 1);

    if (k0 <= qw + 31) {
      f32x4 sT[2][4] = {};
      __builtin_amdgcn_s_setprio(1);
#pragma unroll
      for (int p = 0; p < 4; ++p) {
        const int lrow = p * 16 + l15;
#pragma unroll
        for (int s = 0; s < 4; ++s) {
          const int lbyte = (lrow << 8) + ((s * 64 + l4 * 16) ^ ((lrow & 7) << 4));
          const bf16x8 kf = *(const bf16x8*)((const char*)&Ks[cur][0] + lbyte);
          sT[0][p] = __builtin_amdgcn_mfma_f32_16x16x32_bf16(kf, qf[0][s], sT[0][p], 0, 0, 0);
          sT[1][p] = __builtin_amdgcn_mfma_f32_16x16x32_bf16(kf, qf[1][s], sT[1][p], 0, 0, 0);
        }
      }
      __builtin_amdgcn_s_setprio(0);

      const short* vp = vbase + (size_t)l15 * NS + k0 + l4 * 8;
      bf16x8 vA[8];
#pragma unroll
      for (int t8 = 0; t8 < 8; ++t8)
        vA[t8] = *(const bf16x8*)(vp + (size_t)t8 * 16 * NS);

      const bool full = (k0 + 63 <= qw);
      float pv[2][16];
      float tmax[2] = {-1e30f, -1e30f};
#pragma unroll
      for (int p = 0; p < 4; ++p) {
        const f32x4 bvec = *(const f32x4*)&biasLds[k0 + p * 16 + l4 * 4];
#pragma unroll
        for (int r = 0; r < 4; ++r) {
          const int kg = k0 + p * 16 + l4 * 4 + r;
          float v0 = sT[0][p][r] + bvec[r];
          float v1 = sT[1][p][r] + bvec[r];
          if (!full) {
            v0 = (kg <= qg0) ? v0 : -1e30f;
            v1 = (kg <= qg1) ? v1 : -1e30f;
          }
          pv[0][p * 4 + r] = v0; pv[1][p * 4 + r] = v1;
          tmax[0] = fmaxf(tmax[0], v0);
          tmax[1] = fmaxf(tmax[1], v1);
        }
      }
      float alpha[2];
#pragma unroll
      for (int c = 0; c < 2; ++c) {
        tmax[c] = fmaxf(tmax[c], __shfl_xor(tmax[c], 16, 64));
        tmax[c] = fmaxf(tmax[c], __shfl_xor(tmax[c], 32, 64));
        const float mnew = fmaxf(mrun[c], tmax[c]);
        alpha[c] = __expf(mrun[c] - mnew);
        mrun[c] = mnew;
        float psum = 0.f;
#pragma unroll
        for (int i = 0; i < 16; ++i) {
          pv[c][i] = __expf(pv[c][i] - mnew);
          psum += pv[c][i];
        }
        psum += __shfl_xor(psum, 16, 64);
        psum += __shfl_xor(psum, 32, 64);
        lrun[c] = lrun[c] * alpha[c] + psum;
#pragma unroll
        for (int t8 = 0; t8 < 8; ++t8)
#pragma unroll
          for (int r = 0; r < 4; ++r)
            acc[c][t8][r] *= alpha[c];
      }

#pragma unroll
      for (int c = 0; c < 2; ++c)
#pragma unroll
        for (int p = 0; p < 4; ++p) {
          bf16x4 pk = { (__bf16)pv[c][p * 4 + 0], (__bf16)pv[c][p * 4 + 1],
                        (__bf16)pv[c][p * 4 + 2], (__bf16)pv[c][p * 4 + 3] };
          const int byteoff = ((16 * c + l15) << 7) + (((p * 16 + l4 * 4) << 1) ^ pswzB);
          *(bf16x4*)((char*)myP + byteoff) = pk;
        }
      asm volatile("s_waitcnt lgkmcnt(0)" ::: "memory");

      bf16x8 pfA[2], pfB[2];
#pragma unroll
      for (int c = 0; c < 2; ++c)
        pfA[c] = *(const bf16x8*)((const char*)myP + ((16 * c + l15) << 7) + ((l4 * 16) ^ pswzB));
      bf16x8 vB[8];
#pragma unroll
      for (int t8 = 0; t8 < 8; ++t8)
        vB[t8] = *(const bf16x8*)(vp + 32 + (size_t)t8 * 16 * NS);
      __builtin_amdgcn_s_setprio(1);
#pragma unroll
      for (int t8 = 0; t8 < 8; ++t8) {
        acc[0][t8] = __builtin_amdgcn_mfma_f32_16x16x32_bf16(vA[t8], pfA[0], acc[0][t8], 0, 0, 0);
        acc[1][t8] = __builtin_amdgcn_mfma_f32_16x16x32_bf16(vA[t8], pfA[1], acc[1][t8], 0, 0, 0);
      }
      __builtin_amdgcn_s_setprio(0);
#pragma unroll
      for (int c = 0; c < 2; ++c)
        pfB[c] = *(const bf16x8*)((const char*)myP + ((16 * c + l15) << 7) + ((64 + l4 * 16) ^ pswzB));
      __builtin_amdgcn_s_setprio(1);
#pragma unroll
      for (int t8 = 0; t8 < 8; ++t8) {
        acc[0][t8] = __builtin_amdgcn_mfma_f32_16x16x32_bf16(vB[t8], pfB[0], acc[0][t8], 0, 0, 0);
        acc[1][t8] = __builtin_amdgcn_mfma_f32_16x16x32_bf16(vB[t8], pfB[1], acc[1][t8], 0, 0, 0);
      }
      __builtin_amdgcn_s_setprio(0);
    }

    __syncthreads();
    cur ^= 1;
  }
#undef KSTAGE

#pragma unroll
  for (int c = 0; c < 2; ++c) {
    const float inv = (lrun[c] > 0.f) ? 1.0f / lrun[c] : 0.f;
    short* obase = Ob + ((size_t)bb * NS + qw + 16 * c + l15) * ND + h * NHD + l4 * 4;
#pragma unroll
    for (int t8 = 0; t8 < 8; ++t8) {
      bf16x4 o = { (__bf16)(acc[c][t8][0] * inv), (__bf16)(acc[c][t8][1] * inv),
                   (__bf16)(acc[c][t8][2] * inv), (__bf16)(acc[c][t8][3] * inv) };
      *(bf16x4*)&obase[t8 * 16] = o;
    }
  }
}

extern "C" void kernel_launch(void* const* d_in, const int* in_sizes, int n_in,
                              void* d_out, int out_size, void* d_ws, size_t ws_size,
                              hipStream_t stream) {
  const float* hidden   = (const float*)d_in[0];
  const float* residual = (const float*)d_in[1];
  const float* alibi    = (const float*)d_in[2];
  const float* W_qkv    = (const float*)d_in[3];
  const float* b_qkv    = (const float*)d_in[4];
  const float* W_o      = (const float*)d_in[5];
  const float* b_o      = (const float*)d_in[6];
  const int*   amask    = (const int*)d_in[7];
  float* out = (float*)d_out;

  char* p = (char*)d_ws;
  short* Abuf  = (short*)p; p += (size_t)NM * ND * 2;
  short* WqkvT = (short*)p; p += (size_t)NQKV * ND * 2;
  short* WoT   = (short*)p; p += (size_t)ND * ND * 2;
  short* Qb    = (short*)p; p += (size_t)NB * NH * NS * NHD * 2;
  short* Kb    = (short*)p; p += (size_t)NB * NH * NS * NHD * 2;
  short* Vtb   = (short*)p; p += (size_t)NB * NH * NS * NHD * 2;
  short* Ob    = (short*)p; p += (size_t)NM * ND * 2;

  cvt_bf16_kernel<<<(NM * ND / 4) / 256, 256, 0, stream>>>(hidden, Abuf, NM * ND / 4);
  transpose_cvt_kernel<<<dim3(NQKV / 64, ND / 64), dim3(64, 4), 0, stream>>>(W_qkv, WqkvT, ND, NQKV);
  transpose_cvt_kernel<<<dim3(ND / 64, ND / 64), dim3(64, 4), 0, stream>>>(W_o, WoT, ND, ND);
  gemm_kernel<0><<<dim3((NQKV / 256) * (NM / 256)), 512, 0, stream>>>(
      Abuf, WqkvT, ND, NQKV, NQKV / 256, b_qkv, Qb, Kb, Vtb, nullptr, nullptr);
  attn_kernel<<<dim3(512), 256, 0, stream>>>(Qb, Kb, Vtb, alibi, amask, Ob);
  gemm_kernel<1><<<dim3((ND / 256) * (NM / 256)), 512, 0, stream>>>(
      Ob, WoT, ND, ND, ND / 256, b_o, nullptr, nullptr, nullptr, residual, out);
}

// Round 6
// 358.725 us; speedup vs baseline: 1.0488x; 1.0488x over previous
//
#include <hip/hip_runtime.h>
#include <stdint.h>

typedef __attribute__((ext_vector_type(4))) float f32x4;
typedef __attribute__((ext_vector_type(8))) __bf16 bf16x8;
typedef __attribute__((ext_vector_type(4))) __bf16 bf16x4;

#define NB 2
#define NS 2048
#define ND 2048
#define NH 16
#define NHD 128
#define NM (NB*NS)      // 4096 rows
#define NQKV (3*ND)     // 6144

__device__ __forceinline__ short f2bf(float f) {
  union { float f; uint32_t u; } c; c.f = f;
  uint32_t r = (c.u + 0x7FFFu + ((c.u >> 16) & 1u)) >> 16;
  return (short)r;
}

__device__ __forceinline__ void gl_lds16(const short* g, short* l) {
  __builtin_amdgcn_global_load_lds(
      (const __attribute__((address_space(1))) void*)g,
      (__attribute__((address_space(3))) void*)l, 16, 0, 0);
}

// ---------------- fp32 -> bf16 elementwise ----------------
__global__ __launch_bounds__(256) void cvt_bf16_kernel(const float* __restrict__ in,
                                                       short* __restrict__ out, int n4) {
  int i = blockIdx.x * 256 + threadIdx.x;
  if (i >= n4) return;
  float4 v = ((const float4*)in)[i];
  short4 o;
  o.x = f2bf(v.x); o.y = f2bf(v.y); o.z = f2bf(v.z); o.w = f2bf(v.w);
  ((short4*)out)[i] = o;
}

// ---------------- fp32 [rows][cols] -> bf16 [cols][rows] ----------------
__global__ __launch_bounds__(256) void transpose_cvt_kernel(const float* __restrict__ in,
                                                            short* __restrict__ out,
                                                            int rows, int cols) {
  __shared__ float tile[64][65];
  const int tx = threadIdx.x, ty = threadIdx.y;
  const int r0 = blockIdx.y * 64, c0 = blockIdx.x * 64;
  for (int i = ty; i < 64; i += 4)
    tile[i][tx] = in[(size_t)(r0 + i) * cols + c0 + tx];
  __syncthreads();
  for (int i = ty; i < 64; i += 4)
    out[(size_t)(c0 + i) * rows + r0 + tx] = f2bf(tile[tx][i]);
}

// ---------------- bf16 GEMM, 256x256, BK=64, 8 waves, true 4-phase interleave ----
// Per phase: {ds-read subtile || stage chunk(kt+2) -> barrier -> lgkmcnt(0) ->
// setprio(1) 16xMFMA setprio(0) -> barrier}. Stage targets only regions already
// consumed this tile (guaranteed by per-phase barriers). vmcnt(8) once per tile.
template<int EPI>
__global__ __launch_bounds__(512, 2) void gemm_kernel(
    const short* __restrict__ A, const short* __restrict__ Bt, int K, int N, int nbx,
    const float* __restrict__ bias,
    short* __restrict__ Qb, short* __restrict__ Kb, short* __restrict__ Vtb,
    const float* __restrict__ residual, float* __restrict__ out) {
  const int tid = threadIdx.x;
  const int wid = tid >> 6, l = tid & 63;
  const int l15 = l & 15, l4 = l >> 4;
  const int wr = wid >> 2, wc = wid & 3;

  // T1: XCD gets contiguous chunk of tile space (grid % 8 == 0 -> bijective)
  const int NT = gridDim.x;
  const int flat = blockIdx.x;
  const int swz = (flat & 7) * (NT >> 3) + (flat >> 3);
  const int bx = swz % nbx, by = swz / nbx;
  const int rowBase = by * 256, colBase = bx * 256;

  __shared__ short As[2][256 * 64];   // 64 KB
  __shared__ short Bs[2][256 * 64];   // 64 KB

  f32x4 acc[8][4] = {};

  const int nk = K >> 6;

  // staging lane map: one code-line = 8KB chunk (64 rows x 128B), wave wid covers
  // rows wid*8+(l>>3); LDS dest linear, source col pre-swizzled (T2, rule #21).
  const int crow = wid * 8 + (l >> 3);                    // 0..63 within chunk
  const int scol = ((l & 7) ^ ((l >> 3) & 7)) << 3;       // swizzled source col (elems)

#define STG(ldsbuf, ldsRow0, gptr, grow0, kt0)                                   \
    gl_lds16((gptr) + (size_t)((grow0) + crow) * K + (size_t)(kt0) * 64 + scol,  \
             &(ldsbuf)[(ldsRow0) * 64 + wid * 512])

#define CHUNK_A0(buf, kt0) do { STG(As[buf], 0,   A,  rowBase + 0,   kt0);       \
                                STG(As[buf], 128, A,  rowBase + 128, kt0); } while (0)
#define CHUNK_A1(buf, kt0) do { STG(As[buf], 64,  A,  rowBase + 64,  kt0);       \
                                STG(As[buf], 192, A,  rowBase + 192, kt0); } while (0)
#define CHUNK_B(buf, kt0)  do { STG(Bs[buf], 0,   Bt, colBase + 0,   kt0);       \
                                STG(Bs[buf], 64,  Bt, colBase + 64,  kt0);       \
                                STG(Bs[buf], 128, Bt, colBase + 128, kt0);       \
                                STG(Bs[buf], 192, Bt, colBase + 192, kt0); } while (0)
#define GSTAGE_ALL(buf, kt0) do { CHUNK_A0(buf, kt0); CHUNK_B(buf, kt0);         \
                                  CHUNK_A1(buf, kt0); } while (0)

  bf16x8 af[4][2], bfr0[2][2], bfr1[2][2];
  const int aXor = (l15 & 7) << 4;   // byte XOR; (row&7)==(l15&7) for all frag rows
  const int aColB = l4 * 16;

#define LDA(buf, mh)                                                             \
  _Pragma("unroll")                                                              \
  for (int m_ = 0; m_ < 4; ++m_) {                                               \
    const int r_ = wr * 128 + (mh) * 64 + m_ * 16 + l15;                         \
    _Pragma("unroll")                                                            \
    for (int kk_ = 0; kk_ < 2; ++kk_)                                            \
      af[m_][kk_] = *(const bf16x8*)((const char*)&As[buf][0] + r_ * 128 +       \
                                     ((kk_ * 64 + aColB) ^ aXor));               \
  }
#define LDB(buf, nh, dst)                                                        \
  _Pragma("unroll")                                                              \
  for (int n_ = 0; n_ < 2; ++n_) {                                               \
    const int r_ = wc * 64 + (nh) * 32 + n_ * 16 + l15;                          \
    _Pragma("unroll")                                                            \
    for (int kk_ = 0; kk_ < 2; ++kk_)                                            \
      dst[n_][kk_] = *(const bf16x8*)((const char*)&Bs[buf][0] + r_ * 128 +      \
                                      ((kk_ * 64 + aColB) ^ aXor));              \
  }
#define MMA(mh, nh, bsrc)                                                        \
  _Pragma("unroll")                                                              \
  for (int m_ = 0; m_ < 4; ++m_)                                                 \
    _Pragma("unroll")                                                            \
    for (int n_ = 0; n_ < 2; ++n_)                                               \
      _Pragma("unroll")                                                          \
      for (int kk_ = 0; kk_ < 2; ++kk_)                                          \
        acc[(mh) * 4 + m_][(nh) * 2 + n_] = __builtin_amdgcn_mfma_f32_16x16x32_bf16( \
            af[m_][kk_], bsrc[n_][kk_], acc[(mh) * 4 + m_][(nh) * 2 + n_], 0, 0, 0);

#define SYNC_PRE  do { __builtin_amdgcn_s_barrier();                             \
    asm volatile("s_waitcnt lgkmcnt(0)" ::: "memory");                           \
    __builtin_amdgcn_sched_barrier(0);                                           \
    __builtin_amdgcn_s_setprio(1); } while (0)
#define SYNC_POST do { __builtin_amdgcn_s_setprio(0);                            \
    __builtin_amdgcn_s_barrier();                                                \
    __builtin_amdgcn_sched_barrier(0); } while (0)

  // prologue: prime tiles 0 and 1; wait tile 0 (8 of 16 outstanding)
  GSTAGE_ALL(0, 0);
  GSTAGE_ALL(1, 1);
  asm volatile("s_waitcnt vmcnt(8)" ::: "memory");
  __builtin_amdgcn_s_barrier();
  __builtin_amdgcn_sched_barrier(0);

  for (int kt = 0; kt < nk; ++kt) {
    const int cur = kt & 1;
    const bool pre = (kt + 2 < nk);
    // ph1: read A-mh0 + B-nh0; MMA quadrant (0,0)
    LDA(cur, 0); LDB(cur, 0, bfr0);
    SYNC_PRE; MMA(0, 0, bfr0); SYNC_POST;
    // ph2: read B-nh1; stage A{0-63,128-191} of kt+2 (consumed in ph1)
    LDB(cur, 1, bfr1);
    if (pre) CHUNK_A0(cur, kt + 2);
    SYNC_PRE; MMA(0, 1, bfr1); SYNC_POST;
    // ph3: read A-mh1; stage all B of kt+2 (consumed ph1+ph2)
    LDA(cur, 1);
    if (pre) CHUNK_B(cur, kt + 2);
    SYNC_PRE; MMA(1, 1, bfr1); SYNC_POST;
    // ph4: no ds-read (regs); stage A{64-127,192-255}; counted vmcnt
    if (pre) CHUNK_A1(cur, kt + 2);
    if (pre)                 asm volatile("s_waitcnt vmcnt(8)" ::: "memory");
    else if (kt + 2 == nk)   asm volatile("s_waitcnt vmcnt(0)" ::: "memory");
    SYNC_PRE; MMA(1, 0, bfr0); SYNC_POST;
  }
#undef STG
#undef CHUNK_A0
#undef CHUNK_A1
#undef CHUNK_B
#undef GSTAGE_ALL
#undef LDA
#undef LDB
#undef MMA
#undef SYNC_PRE
#undef SYNC_POST

#pragma unroll
  for (int m = 0; m < 8; ++m) {
#pragma unroll
    for (int n = 0; n < 4; ++n) {
#pragma unroll
      for (int r = 0; r < 4; ++r) {
        const int row = rowBase + wr * 128 + m * 16 + l4 * 4 + r;
        const int col = colBase + wc * 64 + n * 16 + l15;
        float v = acc[m][n][r] + bias[col];
        if (EPI == 0) {
          const int h = col / 384;
          const int sub = col - h * 384;
          const int t = sub >> 7, hd = sub & 127;
          const int bb = row >> 11, s = row & 2047;
          const size_t bh = (size_t)bb * NH + h;
          if (t == 0)      Qb[(bh * NS + s) * NHD + hd] = f2bf(v * 0.08838834764831845f);
          else if (t == 1) Kb[(bh * NS + s) * NHD + hd] = f2bf(v);
          else             Vtb[(bh * NHD + hd) * NS + s] = f2bf(v);
        } else {
          const size_t idx = (size_t)row * N + col;
          out[idx] = v + residual[idx];
        }
      }
    }
  }
}

// ---------------- flash attention v4: QBLK=32/wave, K in LDS (swizzled) ----------------
__global__ __launch_bounds__(256, 2) void attn_kernel(
    const short* __restrict__ Qb, const short* __restrict__ Kb,
    const short* __restrict__ Vtb, const float* __restrict__ alibi,
    const int* __restrict__ amask, short* __restrict__ Ob) {
  const int tid = threadIdx.x;
  const int w = tid >> 6, l = tid & 63;
  const int l15 = l & 15, l4 = l >> 4;
  const int flat = blockIdx.x;
  const int bh = flat & 31;
  const int y = (flat >> 5) & 7, z = flat >> 8;
  const int qt = z ? (15 - y) : y;
  const int bb = bh >> 4, h = bh & 15;
  const int q0 = qt * 128;
  const int qw = q0 + w * 32;
  const int NT = 2 * qt + 2;

  __shared__ float biasLds[NS];
  __shared__ short Ks[2][64 * 128];
  __shared__ short Plds[4][32 * 64];

  {
    const float* abase = alibi + (size_t)bh * NS;
    const int* mbase = amask + (size_t)bb * NS;
    for (int i = tid; i < NS; i += 256)
      biasLds[i] = mbase[i] ? abase[i] : -1e30f;
  }

  const short* kbase = Kb + (size_t)bh * NS * NHD;
  const short* vbase = Vtb + (size_t)bh * NHD * NS;

#define KSTAGE(buf, kt0) do {                                                  \
    _Pragma("unroll")                                                          \
    for (int i_ = 0; i_ < 4; ++i_) {                                           \
      const int Lb_ = w * 4096 + i_ * 1024 + l * 16;                           \
      const int row_ = Lb_ >> 8;                                               \
      const int X_ = (Lb_ & 255) ^ ((row_ & 7) << 4);                          \
      gl_lds16((const short*)((const char*)kbase + (size_t)((kt0) * 64 + row_) * 256 + X_), \
               (short*)((char*)&Ks[buf][0] + (w * 4096 + i_ * 1024)));         \
    }                                                                          \
  } while (0)

  const short* qp = Qb + ((size_t)bh * NS + qw + l15) * NHD + l4 * 8;
  bf16x8 qf[2][4];
#pragma unroll
  for (int c = 0; c < 2; ++c)
#pragma unroll
    for (int s = 0; s < 4; ++s)
      qf[c][s] = *(const bf16x8*)(qp + c * 16 * NHD + s * 32);

  f32x4 acc[2][8] = {};
  float mrun[2] = {-1e30f, -1e30f}, lrun[2] = {0.f, 0.f};

  short* myP = &Plds[w][0];
  const int pswzB = (l15 & 7) << 4;
  const int qg0 = qw + l15, qg1 = qw + 16 + l15;

  KSTAGE(0, 0);
  __syncthreads();
  int cur = 0;

  for (int t = 0; t < NT; ++t) {
    const int k0 = t << 6;
    if (t + 1 < NT) KSTAGE(cur ^ 1, t + 1);

    if (k0 <= qw + 31) {
      f32x4 sT[2][4] = {};
      __builtin_amdgcn_s_setprio(1);
#pragma unroll
      for (int p = 0; p < 4; ++p) {
        const int lrow = p * 16 + l15;
#pragma unroll
        for (int s = 0; s < 4; ++s) {
          const int lbyte = (lrow << 8) + ((s * 64 + l4 * 16) ^ ((lrow & 7) << 4));
          const bf16x8 kf = *(const bf16x8*)((const char*)&Ks[cur][0] + lbyte);
          sT[0][p] = __builtin_amdgcn_mfma_f32_16x16x32_bf16(kf, qf[0][s], sT[0][p], 0, 0, 0);
          sT[1][p] = __builtin_amdgcn_mfma_f32_16x16x32_bf16(kf, qf[1][s], sT[1][p], 0, 0, 0);
        }
      }
      __builtin_amdgcn_s_setprio(0);

      const short* vp = vbase + (size_t)l15 * NS + k0 + l4 * 8;
      bf16x8 vA[8];
#pragma unroll
      for (int t8 = 0; t8 < 8; ++t8)
        vA[t8] = *(const bf16x8*)(vp + (size_t)t8 * 16 * NS);

      const bool full = (k0 + 63 <= qw);
      float pv[2][16];
      float tmax[2] = {-1e30f, -1e30f};
#pragma unroll
      for (int p = 0; p < 4; ++p) {
        const f32x4 bvec = *(const f32x4*)&biasLds[k0 + p * 16 + l4 * 4];
#pragma unroll
        for (int r = 0; r < 4; ++r) {
          const int kg = k0 + p * 16 + l4 * 4 + r;
          float v0 = sT[0][p][r] + bvec[r];
          float v1 = sT[1][p][r] + bvec[r];
          if (!full) {
            v0 = (kg <= qg0) ? v0 : -1e30f;
            v1 = (kg <= qg1) ? v1 : -1e30f;
          }
          pv[0][p * 4 + r] = v0; pv[1][p * 4 + r] = v1;
          tmax[0] = fmaxf(tmax[0], v0);
          tmax[1] = fmaxf(tmax[1], v1);
        }
      }
      float alpha[2];
#pragma unroll
      for (int c = 0; c < 2; ++c) {
        tmax[c] = fmaxf(tmax[c], __shfl_xor(tmax[c], 16, 64));
        tmax[c] = fmaxf(tmax[c], __shfl_xor(tmax[c], 32, 64));
        const float mnew = fmaxf(mrun[c], tmax[c]);
        alpha[c] = __expf(mrun[c] - mnew);
        mrun[c] = mnew;
        float psum = 0.f;
#pragma unroll
        for (int i = 0; i < 16; ++i) {
          pv[c][i] = __expf(pv[c][i] - mnew);
          psum += pv[c][i];
        }
        psum += __shfl_xor(psum, 16, 64);
        psum += __shfl_xor(psum, 32, 64);
        lrun[c] = lrun[c] * alpha[c] + psum;
#pragma unroll
        for (int t8 = 0; t8 < 8; ++t8)
#pragma unroll
          for (int r = 0; r < 4; ++r)
            acc[c][t8][r] *= alpha[c];
      }

#pragma unroll
      for (int c = 0; c < 2; ++c)
#pragma unroll
        for (int p = 0; p < 4; ++p) {
          bf16x4 pk = { (__bf16)pv[c][p * 4 + 0], (__bf16)pv[c][p * 4 + 1],
                        (__bf16)pv[c][p * 4 + 2], (__bf16)pv[c][p * 4 + 3] };
          const int byteoff = ((16 * c + l15) << 7) + (((p * 16 + l4 * 4) << 1) ^ pswzB);
          *(bf16x4*)((char*)myP + byteoff) = pk;
        }
      asm volatile("s_waitcnt lgkmcnt(0)" ::: "memory");

      bf16x8 pfA[2], pfB[2];
#pragma unroll
      for (int c = 0; c < 2; ++c)
        pfA[c] = *(const bf16x8*)((const char*)myP + ((16 * c + l15) << 7) + ((l4 * 16) ^ pswzB));
      bf16x8 vB[8];
#pragma unroll
      for (int t8 = 0; t8 < 8; ++t8)
        vB[t8] = *(const bf16x8*)(vp + 32 + (size_t)t8 * 16 * NS);
      __builtin_amdgcn_s_setprio(1);
#pragma unroll
      for (int t8 = 0; t8 < 8; ++t8) {
        acc[0][t8] = __builtin_amdgcn_mfma_f32_16x16x32_bf16(vA[t8], pfA[0], acc[0][t8], 0, 0, 0);
        acc[1][t8] = __builtin_amdgcn_mfma_f32_16x16x32_bf16(vA[t8], pfA[1], acc[1][t8], 0, 0, 0);
      }
      __builtin_amdgcn_s_setprio(0);
#pragma unroll
      for (int c = 0; c < 2; ++c)
        pfB[c] = *(const bf16x8*)((const char*)myP + ((16 * c + l15) << 7) + ((64 + l4 * 16) ^ pswzB));
      __builtin_amdgcn_s_setprio(1);
#pragma unroll
      for (int t8 = 0; t8 < 8; ++t8) {
        acc[0][t8] = __builtin_amdgcn_mfma_f32_16x16x32_bf16(vB[t8], pfB[0], acc[0][t8], 0, 0, 0);
        acc[1][t8] = __builtin_amdgcn_mfma_f32_16x16x32_bf16(vB[t8], pfB[1], acc[1][t8], 0, 0, 0);
      }
      __builtin_amdgcn_s_setprio(0);
    }

    __syncthreads();
    cur ^= 1;
  }
#undef KSTAGE

#pragma unroll
  for (int c = 0; c < 2; ++c) {
    const float inv = (lrun[c] > 0.f) ? 1.0f / lrun[c] : 0.f;
    short* obase = Ob + ((size_t)bb * NS + qw + 16 * c + l15) * ND + h * NHD + l4 * 4;
#pragma unroll
    for (int t8 = 0; t8 < 8; ++t8) {
      bf16x4 o = { (__bf16)(acc[c][t8][0] * inv), (__bf16)(acc[c][t8][1] * inv),
                   (__bf16)(acc[c][t8][2] * inv), (__bf16)(acc[c][t8][3] * inv) };
      *(bf16x4*)&obase[t8 * 16] = o;
    }
  }
}

extern "C" void kernel_launch(void* const* d_in, const int* in_sizes, int n_in,
                              void* d_out, int out_size, void* d_ws, size_t ws_size,
                              hipStream_t stream) {
  const float* hidden   = (const float*)d_in[0];
  const float* residual = (const float*)d_in[1];
  const float* alibi    = (const float*)d_in[2];
  const float* W_qkv    = (const float*)d_in[3];
  const float* b_qkv    = (const float*)d_in[4];
  const float* W_o      = (const float*)d_in[5];
  const float* b_o      = (const float*)d_in[6];
  const int*   amask    = (const int*)d_in[7];
  float* out = (float*)d_out;

  char* p = (char*)d_ws;
  short* Abuf  = (short*)p; p += (size_t)NM * ND * 2;
  short* WqkvT = (short*)p; p += (size_t)NQKV * ND * 2;
  short* WoT   = (short*)p; p += (size_t)ND * ND * 2;
  short* Qb    = (short*)p; p += (size_t)NB * NH * NS * NHD * 2;
  short* Kb    = (short*)p; p += (size_t)NB * NH * NS * NHD * 2;
  short* Vtb   = (short*)p; p += (size_t)NB * NH * NS * NHD * 2;
  short* Ob    = (short*)p; p += (size_t)NM * ND * 2;

  cvt_bf16_kernel<<<(NM * ND / 4) / 256, 256, 0, stream>>>(hidden, Abuf, NM * ND / 4);
  transpose_cvt_kernel<<<dim3(NQKV / 64, ND / 64), dim3(64, 4), 0, stream>>>(W_qkv, WqkvT, ND, NQKV);
  transpose_cvt_kernel<<<dim3(ND / 64, ND / 64), dim3(64, 4), 0, stream>>>(W_o, WoT, ND, ND);
  gemm_kernel<0><<<dim3((NQKV / 256) * (NM / 256)), 512, 0, stream>>>(
      Abuf, WqkvT, ND, NQKV, NQKV / 256, b_qkv, Qb, Kb, Vtb, nullptr, nullptr);
  attn_kernel<<<dim3(512), 256, 0, stream>>>(Qb, Kb, Vtb, alibi, amask, Ob);
  gemm_kernel<1><<<dim3((ND / 256) * (NM / 256)), 512, 0, stream>>>(
      Ob, WoT, ND, ND, ND / 256, b_o, nullptr, nullptr, nullptr, residual, out);
}

// Round 7
// 352.837 us; speedup vs baseline: 1.0663x; 1.0167x over previous
//
#include <hip/hip_runtime.h>
#include <stdint.h>

typedef __attribute__((ext_vector_type(4))) float f32x4;
typedef __attribute__((ext_vector_type(8))) __bf16 bf16x8;
typedef __attribute__((ext_vector_type(4))) __bf16 bf16x4;

#define NB 2
#define NS 2048
#define ND 2048
#define NH 16
#define NHD 128
#define NM (NB*NS)      // 4096 rows
#define NQKV (3*ND)     // 6144

__device__ __forceinline__ short f2bf(float f) {
  union { float f; uint32_t u; } c; c.f = f;
  uint32_t r = (c.u + 0x7FFFu + ((c.u >> 16) & 1u)) >> 16;
  return (short)r;
}

__device__ __forceinline__ void gl_lds16(const short* g, short* l) {
  __builtin_amdgcn_global_load_lds(
      (const __attribute__((address_space(1))) void*)g,
      (__attribute__((address_space(3))) void*)l, 16, 0, 0);
}

// ---------------- fp32 -> bf16 elementwise ----------------
__global__ __launch_bounds__(256) void cvt_bf16_kernel(const float* __restrict__ in,
                                                       short* __restrict__ out, int n4) {
  int i = blockIdx.x * 256 + threadIdx.x;
  if (i >= n4) return;
  float4 v = ((const float4*)in)[i];
  short4 o;
  o.x = f2bf(v.x); o.y = f2bf(v.y); o.z = f2bf(v.z); o.w = f2bf(v.w);
  ((short4*)out)[i] = o;
}

// ---------------- fp32 [rows][cols] -> bf16 [cols][rows] ----------------
__global__ __launch_bounds__(256) void transpose_cvt_kernel(const float* __restrict__ in,
                                                            short* __restrict__ out,
                                                            int rows, int cols) {
  __shared__ float tile[64][65];
  const int tx = threadIdx.x, ty = threadIdx.y;
  const int r0 = blockIdx.y * 64, c0 = blockIdx.x * 64;
  for (int i = ty; i < 64; i += 4)
    tile[i][tx] = in[(size_t)(r0 + i) * cols + c0 + tx];
  __syncthreads();
  for (int i = ty; i < 64; i += 4)
    out[(size_t)(c0 + i) * rows + r0 + tx] = f2bf(tile[tx][i]);
}

// ---------------- bf16 GEMM, 256x128 tile, BK=64, 8 waves (4Mx2N), 4-phase ----
// Balanced grids: QKV 48*16=768=3x256, O-proj 16*16=256=1x256. LDS 96KB.
// T2 swizzle (LDS linear dest + pre-swizzled source + XOR read), counted vmcnt(6),
// setprio around MFMA, per-phase barriers, by-fastest XCD chunking.
template<int EPI>
__global__ __launch_bounds__(512, 2) void gemm_kernel(
    const short* __restrict__ A, const short* __restrict__ Bt, int K, int N, int nbx,
    const float* __restrict__ bias,
    short* __restrict__ Qb, short* __restrict__ Kb, short* __restrict__ Vtb,
    const float* __restrict__ residual, float* __restrict__ out) {
  const int tid = threadIdx.x;
  const int wid = tid >> 6, l = tid & 63;
  const int l15 = l & 15, l4 = l >> 4;
  const int wr = wid >> 1, wc = wid & 1;

  // T1: XCD gets contiguous chunk; by (rows) fastest -> per-XCD B slice is L2-sized
  const int NT = gridDim.x;
  const int flat = blockIdx.x;
  const int swz = (flat & 7) * (NT >> 3) + (flat >> 3);
  const int by = swz & 15, bx = swz >> 4;       // nby = 4096/256 = 16 (fixed)
  const int rowBase = by * 256, colBase = bx * 128;

  __shared__ short As[2][256 * 64];   // 64 KB
  __shared__ short Bs[2][128 * 64];   // 32 KB

  f32x4 acc[4][4] = {};
  const int nk = K >> 6;

  // staging: one inst = 8KB chunk (64 rows x 128B); LDS dest linear,
  // source col pre-swizzled (T2, both-sides rule)
  const int crow = wid * 8 + (l >> 3);
  const int scol = ((l & 7) ^ ((l >> 3) & 7)) << 3;

#define STG(ldsbuf, ldsRow0, gptr, grow0, kt0)                                   \
    gl_lds16((gptr) + (size_t)((grow0) + crow) * K + (size_t)(kt0) * 64 + scol,  \
             &(ldsbuf)[(ldsRow0) * 64 + wid * 512])
#define STG_A01(buf, kt0) do { STG(As[buf], 0,   A,  rowBase + 0,   kt0);        \
                               STG(As[buf], 64,  A,  rowBase + 64,  kt0); } while (0)
#define STG_A23(buf, kt0) do { STG(As[buf], 128, A,  rowBase + 128, kt0);        \
                               STG(As[buf], 192, A,  rowBase + 192, kt0); } while (0)
#define STG_B(buf, kt0)   do { STG(Bs[buf], 0,   Bt, colBase + 0,   kt0);        \
                               STG(Bs[buf], 64,  Bt, colBase + 64,  kt0); } while (0)

  bf16x8 afA[2][2], afB[2][2], bfA[2][2], bfB[2][2];
  const int aXor = (l15 & 7) << 4;
  const int aColB = l4 * 16;

#define LDA(buf, mh, dst)                                                        \
  _Pragma("unroll")                                                              \
  for (int m_ = 0; m_ < 2; ++m_) {                                               \
    const int r_ = wr * 64 + (mh) * 32 + m_ * 16 + l15;                          \
    _Pragma("unroll")                                                            \
    for (int kk_ = 0; kk_ < 2; ++kk_)                                            \
      dst[m_][kk_] = *(const bf16x8*)((const char*)&As[buf][0] + r_ * 128 +      \
                                      ((kk_ * 64 + aColB) ^ aXor));              \
  }
#define LDB(buf, nh, dst)                                                        \
  _Pragma("unroll")                                                              \
  for (int n_ = 0; n_ < 2; ++n_) {                                               \
    const int r_ = wc * 64 + (nh) * 32 + n_ * 16 + l15;                          \
    _Pragma("unroll")                                                            \
    for (int kk_ = 0; kk_ < 2; ++kk_)                                            \
      dst[n_][kk_] = *(const bf16x8*)((const char*)&Bs[buf][0] + r_ * 128 +      \
                                      ((kk_ * 64 + aColB) ^ aXor));              \
  }
#define MMA(mh, nh, asrc, bsrc)                                                  \
  _Pragma("unroll")                                                              \
  for (int m_ = 0; m_ < 2; ++m_)                                                 \
    _Pragma("unroll")                                                            \
    for (int n_ = 0; n_ < 2; ++n_)                                               \
      _Pragma("unroll")                                                          \
      for (int kk_ = 0; kk_ < 2; ++kk_)                                          \
        acc[(mh) * 2 + m_][(nh) * 2 + n_] = __builtin_amdgcn_mfma_f32_16x16x32_bf16( \
            asrc[m_][kk_], bsrc[n_][kk_], acc[(mh) * 2 + m_][(nh) * 2 + n_], 0, 0, 0);

#define SYNC_PRE  do { __builtin_amdgcn_s_barrier();                             \
    asm volatile("s_waitcnt lgkmcnt(0)" ::: "memory");                           \
    __builtin_amdgcn_sched_barrier(0);                                           \
    __builtin_amdgcn_s_setprio(1); } while (0)
#define SYNC_POST do { __builtin_amdgcn_s_setprio(0);                            \
    __builtin_amdgcn_s_barrier();                                                \
    __builtin_amdgcn_sched_barrier(0); } while (0)

  // prologue: prime tiles 0,1 (12 loads); wait tile 0 (6 remain in flight)
  STG_A01(0, 0); STG_A23(0, 0); STG_B(0, 0);
  STG_A01(1, 1); STG_A23(1, 1); STG_B(1, 1);
  asm volatile("s_waitcnt vmcnt(6)" ::: "memory");
  __builtin_amdgcn_s_barrier();
  __builtin_amdgcn_sched_barrier(0);

  for (int kt = 0; kt < nk; ++kt) {
    const int cur = kt & 1;
    const bool pre = (kt + 2 < nk);
    // ph1: A-mh0 + B-nh0 -> MMA(0,0)
    LDA(cur, 0, afA); LDB(cur, 0, bfA);
    SYNC_PRE; MMA(0, 0, afA, bfA); SYNC_POST;
    // ph2: A-mh1 -> MMA(1,0)  (A fully read after this phase)
    LDA(cur, 1, afB);
    SYNC_PRE; MMA(1, 0, afB, bfA); SYNC_POST;
    // ph3: B-nh1; stage A rows 0-127 of kt+2 -> MMA(1,1)
    LDB(cur, 1, bfB);
    if (pre) STG_A01(cur, kt + 2);
    SYNC_PRE; MMA(1, 1, afB, bfB); SYNC_POST;
    // ph4: stage A rows 128-255 + all B of kt+2; counted vmcnt -> MMA(0,1)
    if (pre) {
      STG_A23(cur, kt + 2); STG_B(cur, kt + 2);
      asm volatile("s_waitcnt vmcnt(6)" ::: "memory");
    } else if (kt + 2 == nk) {
      asm volatile("s_waitcnt vmcnt(0)" ::: "memory");
    }
    SYNC_PRE; MMA(0, 1, afA, bfB); SYNC_POST;
  }
#undef STG
#undef STG_A01
#undef STG_A23
#undef STG_B
#undef LDA
#undef LDB
#undef MMA
#undef SYNC_PRE
#undef SYNC_POST

#pragma unroll
  for (int m = 0; m < 4; ++m) {
#pragma unroll
    for (int n = 0; n < 4; ++n) {
#pragma unroll
      for (int r = 0; r < 4; ++r) {
        const int row = rowBase + wr * 64 + m * 16 + l4 * 4 + r;
        const int col = colBase + wc * 64 + n * 16 + l15;
        float v = acc[m][n][r] + bias[col];
        if (EPI == 0) {
          const int h = col / 384;
          const int sub = col - h * 384;
          const int t = sub >> 7, hd = sub & 127;
          const int bb = row >> 11, s = row & 2047;
          const size_t bh = (size_t)bb * NH + h;
          if (t == 0)      Qb[(bh * NS + s) * NHD + hd] = f2bf(v * 0.08838834764831845f);
          else if (t == 1) Kb[(bh * NS + s) * NHD + hd] = f2bf(v);
          else             Vtb[(bh * NHD + hd) * NS + s] = f2bf(v);
        } else {
          const size_t idx = (size_t)row * N + col;
          out[idx] = v + residual[idx];
        }
      }
    }
  }
}

// ---------------- flash attention v4: QBLK=32/wave, K in LDS (swizzled) ----------------
__global__ __launch_bounds__(256, 2) void attn_kernel(
    const short* __restrict__ Qb, const short* __restrict__ Kb,
    const short* __restrict__ Vtb, const float* __restrict__ alibi,
    const int* __restrict__ amask, short* __restrict__ Ob) {
  const int tid = threadIdx.x;
  const int w = tid >> 6, l = tid & 63;
  const int l15 = l & 15, l4 = l >> 4;
  const int flat = blockIdx.x;
  const int bh = flat & 31;
  const int y = (flat >> 5) & 7, z = flat >> 8;
  const int qt = z ? (15 - y) : y;
  const int bb = bh >> 4, h = bh & 15;
  const int q0 = qt * 128;
  const int qw = q0 + w * 32;
  const int NT = 2 * qt + 2;

  __shared__ float biasLds[NS];
  __shared__ short Ks[2][64 * 128];
  __shared__ short Plds[4][32 * 64];

  {
    const float* abase = alibi + (size_t)bh * NS;
    const int* mbase = amask + (size_t)bb * NS;
    for (int i = tid; i < NS; i += 256)
      biasLds[i] = mbase[i] ? abase[i] : -1e30f;
  }

  const short* kbase = Kb + (size_t)bh * NS * NHD;
  const short* vbase = Vtb + (size_t)bh * NHD * NS;

#define KSTAGE(buf, kt0) do {                                                  \
    _Pragma("unroll")                                                          \
    for (int i_ = 0; i_ < 4; ++i_) {                                           \
      const int Lb_ = w * 4096 + i_ * 1024 + l * 16;                           \
      const int row_ = Lb_ >> 8;                                               \
      const int X_ = (Lb_ & 255) ^ ((row_ & 7) << 4);                          \
      gl_lds16((const short*)((const char*)kbase + (size_t)((kt0) * 64 + row_) * 256 + X_), \
               (short*)((char*)&Ks[buf][0] + (w * 4096 + i_ * 1024)));         \
    }                                                                          \
  } while (0)

  const short* qp = Qb + ((size_t)bh * NS + qw + l15) * NHD + l4 * 8;
  bf16x8 qf[2][4];
#pragma unroll
  for (int c = 0; c < 2; ++c)
#pragma unroll
    for (int s = 0; s < 4; ++s)
      qf[c][s] = *(const bf16x8*)(qp + c * 16 * NHD + s * 32);

  f32x4 acc[2][8] = {};
  float mrun[2] = {-1e30f, -1e30f}, lrun[2] = {0.f, 0.f};

  short* myP = &Plds[w][0];
  const int pswzB = (l15 & 7) << 4;
  const int qg0 = qw + l15, qg1 = qw + 16 + l15;

  KSTAGE(0, 0);
  __syncthreads();
  int cur = 0;

  for (int t = 0; t < NT; ++t) {
    const int k0 = t << 6;
    if (t + 1 < NT) KSTAGE(cur ^ 1, t + 1);

    if (k0 <= qw + 31) {
      f32x4 sT[2][4] = {};
      __builtin_amdgcn_s_setprio(1);
#pragma unroll
      for (int p = 0; p < 4; ++p) {
        const int lrow = p * 16 + l15;
#pragma unroll
        for (int s = 0; s < 4; ++s) {
          const int lbyte = (lrow << 8) + ((s * 64 + l4 * 16) ^ ((lrow & 7) << 4));
          const bf16x8 kf = *(const bf16x8*)((const char*)&Ks[cur][0] + lbyte);
          sT[0][p] = __builtin_amdgcn_mfma_f32_16x16x32_bf16(kf, qf[0][s], sT[0][p], 0, 0, 0);
          sT[1][p] = __builtin_amdgcn_mfma_f32_16x16x32_bf16(kf, qf[1][s], sT[1][p], 0, 0, 0);
        }
      }
      __builtin_amdgcn_s_setprio(0);

      const short* vp = vbase + (size_t)l15 * NS + k0 + l4 * 8;
      bf16x8 vA[8];
#pragma unroll
      for (int t8 = 0; t8 < 8; ++t8)
        vA[t8] = *(const bf16x8*)(vp + (size_t)t8 * 16 * NS);

      const bool full = (k0 + 63 <= qw);
      float pv[2][16];
      float tmax[2] = {-1e30f, -1e30f};
#pragma unroll
      for (int p = 0; p < 4; ++p) {
        const f32x4 bvec = *(const f32x4*)&biasLds[k0 + p * 16 + l4 * 4];
#pragma unroll
        for (int r = 0; r < 4; ++r) {
          const int kg = k0 + p * 16 + l4 * 4 + r;
          float v0 = sT[0][p][r] + bvec[r];
          float v1 = sT[1][p][r] + bvec[r];
          if (!full) {
            v0 = (kg <= qg0) ? v0 : -1e30f;
            v1 = (kg <= qg1) ? v1 : -1e30f;
          }
          pv[0][p * 4 + r] = v0; pv[1][p * 4 + r] = v1;
          tmax[0] = fmaxf(tmax[0], v0);
          tmax[1] = fmaxf(tmax[1], v1);
        }
      }
      float alpha[2];
#pragma unroll
      for (int c = 0; c < 2; ++c) {
        tmax[c] = fmaxf(tmax[c], __shfl_xor(tmax[c], 16, 64));
        tmax[c] = fmaxf(tmax[c], __shfl_xor(tmax[c], 32, 64));
        const float mnew = fmaxf(mrun[c], tmax[c]);
        alpha[c] = __expf(mrun[c] - mnew);
        mrun[c] = mnew;
        float psum = 0.f;
#pragma unroll
        for (int i = 0; i < 16; ++i) {
          pv[c][i] = __expf(pv[c][i] - mnew);
          psum += pv[c][i];
        }
        psum += __shfl_xor(psum, 16, 64);
        psum += __shfl_xor(psum, 32, 64);
        lrun[c] = lrun[c] * alpha[c] + psum;
#pragma unroll
        for (int t8 = 0; t8 < 8; ++t8)
#pragma unroll
          for (int r = 0; r < 4; ++r)
            acc[c][t8][r] *= alpha[c];
      }

#pragma unroll
      for (int c = 0; c < 2; ++c)
#pragma unroll
        for (int p = 0; p < 4; ++p) {
          bf16x4 pk = { (__bf16)pv[c][p * 4 + 0], (__bf16)pv[c][p * 4 + 1],
                        (__bf16)pv[c][p * 4 + 2], (__bf16)pv[c][p * 4 + 3] };
          const int byteoff = ((16 * c + l15) << 7) + (((p * 16 + l4 * 4) << 1) ^ pswzB);
          *(bf16x4*)((char*)myP + byteoff) = pk;
        }
      asm volatile("s_waitcnt lgkmcnt(0)" ::: "memory");

      bf16x8 pfA[2], pfB[2];
#pragma unroll
      for (int c = 0; c < 2; ++c)
        pfA[c] = *(const bf16x8*)((const char*)myP + ((16 * c + l15) << 7) + ((l4 * 16) ^ pswzB));
      bf16x8 vB[8];
#pragma unroll
      for (int t8 = 0; t8 < 8; ++t8)
        vB[t8] = *(const bf16x8*)(vp + 32 + (size_t)t8 * 16 * NS);
      __builtin_amdgcn_s_setprio(1);
#pragma unroll
      for (int t8 = 0; t8 < 8; ++t8) {
        acc[0][t8] = __builtin_amdgcn_mfma_f32_16x16x32_bf16(vA[t8], pfA[0], acc[0][t8], 0, 0, 0);
        acc[1][t8] = __builtin_amdgcn_mfma_f32_16x16x32_bf16(vA[t8], pfA[1], acc[1][t8], 0, 0, 0);
      }
      __builtin_amdgcn_s_setprio(0);
#pragma unroll
      for (int c = 0; c < 2; ++c)
        pfB[c] = *(const bf16x8*)((const char*)myP + ((16 * c + l15) << 7) + ((64 + l4 * 16) ^ pswzB));
      __builtin_amdgcn_s_setprio(1);
#pragma unroll
      for (int t8 = 0; t8 < 8; ++t8) {
        acc[0][t8] = __builtin_amdgcn_mfma_f32_16x16x32_bf16(vB[t8], pfB[0], acc[0][t8], 0, 0, 0);
        acc[1][t8] = __builtin_amdgcn_mfma_f32_16x16x32_bf16(vB[t8], pfB[1], acc[1][t8], 0, 0, 0);
      }
      __builtin_amdgcn_s_setprio(0);
    }

    __syncthreads();
    cur ^= 1;
  }
#undef KSTAGE

#pragma unroll
  for (int c = 0; c < 2; ++c) {
    const float inv = (lrun[c] > 0.f) ? 1.0f / lrun[c] : 0.f;
    short* obase = Ob + ((size_t)bb * NS + qw + 16 * c + l15) * ND + h * NHD + l4 * 4;
#pragma unroll
    for (int t8 = 0; t8 < 8; ++t8) {
      bf16x4 o = { (__bf16)(acc[c][t8][0] * inv), (__bf16)(acc[c][t8][1] * inv),
                   (__bf16)(acc[c][t8][2] * inv), (__bf16)(acc[c][t8][3] * inv) };
      *(bf16x4*)&obase[t8 * 16] = o;
    }
  }
}

extern "C" void kernel_launch(void* const* d_in, const int* in_sizes, int n_in,
                              void* d_out, int out_size, void* d_ws, size_t ws_size,
                              hipStream_t stream) {
  const float* hidden   = (const float*)d_in[0];
  const float* residual = (const float*)d_in[1];
  const float* alibi    = (const float*)d_in[2];
  const float* W_qkv    = (const float*)d_in[3];
  const float* b_qkv    = (const float*)d_in[4];
  const float* W_o      = (const float*)d_in[5];
  const float* b_o      = (const float*)d_in[6];
  const int*   amask    = (const int*)d_in[7];
  float* out = (float*)d_out;

  char* p = (char*)d_ws;
  short* Abuf  = (short*)p; p += (size_t)NM * ND * 2;
  short* WqkvT = (short*)p; p += (size_t)NQKV * ND * 2;
  short* WoT   = (short*)p; p += (size_t)ND * ND * 2;
  short* Qb    = (short*)p; p += (size_t)NB * NH * NS * NHD * 2;
  short* Kb    = (short*)p; p += (size_t)NB * NH * NS * NHD * 2;
  short* Vtb   = (short*)p; p += (size_t)NB * NH * NS * NHD * 2;
  short* Ob    = (short*)p; p += (size_t)NM * ND * 2;

  cvt_bf16_kernel<<<(NM * ND / 4) / 256, 256, 0, stream>>>(hidden, Abuf, NM * ND / 4);
  transpose_cvt_kernel<<<dim3(NQKV / 64, ND / 64), dim3(64, 4), 0, stream>>>(W_qkv, WqkvT, ND, NQKV);
  transpose_cvt_kernel<<<dim3(ND / 64, ND / 64), dim3(64, 4), 0, stream>>>(W_o, WoT, ND, ND);
  gemm_kernel<0><<<dim3((NQKV / 128) * (NM / 256)), 512, 0, stream>>>(
      Abuf, WqkvT, ND, NQKV, NQKV / 128, b_qkv, Qb, Kb, Vtb, nullptr, nullptr);
  attn_kernel<<<dim3(512), 256, 0, stream>>>(Qb, Kb, Vtb, alibi, amask, Ob);
  gemm_kernel<1><<<dim3((ND / 128) * (NM / 256)), 512, 0, stream>>>(
      Ob, WoT, ND, ND, ND / 128, b_o, nullptr, nullptr, nullptr, residual, out);
}

// Round 8
// 324.616 us; speedup vs baseline: 1.1590x; 1.0869x over previous
//
#include <hip/hip_runtime.h>
#include <stdint.h>

typedef __attribute__((ext_vector_type(4))) float f32x4;
typedef __attribute__((ext_vector_type(8))) __bf16 bf16x8;
typedef __attribute__((ext_vector_type(4))) __bf16 bf16x4;

#define NB 2
#define NS 2048
#define ND 2048
#define NH 16
#define NHD 128
#define NM (NB*NS)      // 4096 rows
#define NQKV (3*ND)     // 6144

__device__ __forceinline__ short f2bf(float f) {
  union { float f; uint32_t u; } c; c.f = f;
  uint32_t r = (c.u + 0x7FFFu + ((c.u >> 16) & 1u)) >> 16;
  return (short)r;
}

__device__ __forceinline__ void gl_lds16(const short* g, short* l) {
  __builtin_amdgcn_global_load_lds(
      (const __attribute__((address_space(1))) void*)g,
      (__attribute__((address_space(3))) void*)l, 16, 0, 0);
}

// ---------------- fp32 -> bf16 elementwise ----------------
__global__ __launch_bounds__(256) void cvt_bf16_kernel(const float* __restrict__ in,
                                                       short* __restrict__ out, int n4) {
  int i = blockIdx.x * 256 + threadIdx.x;
  if (i >= n4) return;
  float4 v = ((const float4*)in)[i];
  short4 o;
  o.x = f2bf(v.x); o.y = f2bf(v.y); o.z = f2bf(v.z); o.w = f2bf(v.w);
  ((short4*)out)[i] = o;
}

// ---------------- fp32 [rows][cols] -> bf16 [cols][rows] ----------------
__global__ __launch_bounds__(256) void transpose_cvt_kernel(const float* __restrict__ in,
                                                            short* __restrict__ out,
                                                            int rows, int cols) {
  __shared__ float tile[64][65];
  const int tx = threadIdx.x, ty = threadIdx.y;
  const int r0 = blockIdx.y * 64, c0 = blockIdx.x * 64;
  for (int i = ty; i < 64; i += 4)
    tile[i][tx] = in[(size_t)(r0 + i) * cols + c0 + tx];
  __syncthreads();
  for (int i = ty; i < 64; i += 4)
    out[(size_t)(c0 + i) * rows + r0 + tx] = f2bf(tile[tx][i]);
}

// ---------------- bf16 GEMM, 256x128, BK=64, 8 waves (4Mx2N), reg-pipelined ----
// 2 phases per K-tile. Each phase ds-reads the NEXT phase's fragments and waits
// lgkmcnt(this-phase count) so consuming MFMAs never stall on LDS. A-frags
// double-buffered in regs (static idx, kt+=2 unroll); counted vmcnt(4)/K-tile.
template<int EPI>
__global__ __launch_bounds__(512, 2) void gemm_kernel(
    const short* __restrict__ A, const short* __restrict__ Bt, int K, int N, int nbx,
    const float* __restrict__ bias,
    short* __restrict__ Qb, short* __restrict__ Kb, short* __restrict__ Vtb,
    const float* __restrict__ residual, float* __restrict__ out) {
  const int tid = threadIdx.x;
  const int wid = tid >> 6, l = tid & 63;
  const int l15 = l & 15, l4 = l >> 4;
  const int wr = wid >> 1, wc = wid & 1;

  // T1: XCD-contiguous remap, bx fastest (round-6 style: lower FETCH)
  const int NTg = gridDim.x;
  const int flat = blockIdx.x;
  const int swz = (flat & 7) * (NTg >> 3) + (flat >> 3);
  const int bx = swz % nbx, by = swz / nbx;
  const int rowBase = by * 256, colBase = bx * 128;

  __shared__ short As[2][256 * 64];   // 64 KB
  __shared__ short Bs[2][128 * 64];   // 32 KB

  f32x4 acc[4][4] = {};
  const int nk = K >> 6;

  // staging: one inst = 8KB chunk (64 rows x 128B); LDS dest linear,
  // source col pre-swizzled (T2 both-sides rule)
  const int crow = wid * 8 + (l >> 3);
  const int scol = ((l & 7) ^ ((l >> 3) & 7)) << 3;

#define STG(ldsbuf, ldsRow0, gptr, grow0, kt0)                                   \
    gl_lds16((gptr) + (size_t)((grow0) + crow) * K + (size_t)(kt0) * 64 + scol,  \
             &(ldsbuf)[(ldsRow0) * 64 + wid * 512])
#define STG_A(buf, kt0) do { STG(As[buf], 0,   A,  rowBase + 0,   kt0);          \
                             STG(As[buf], 64,  A,  rowBase + 64,  kt0);          \
                             STG(As[buf], 128, A,  rowBase + 128, kt0);          \
                             STG(As[buf], 192, A,  rowBase + 192, kt0); } while (0)
#define STG_B(buf, kt0) do { STG(Bs[buf], 0,   Bt, colBase + 0,   kt0);          \
                             STG(Bs[buf], 64,  Bt, colBase + 64,  kt0); } while (0)

  bf16x8 afS0[4][2], afS1[4][2], bfLo[2][2], bfHi[2][2];
  const int aXor = (l15 & 7) << 4;
  const int aColB = l4 * 16;

#define LDA(buf, DST)                                                            \
  _Pragma("unroll")                                                              \
  for (int m_ = 0; m_ < 4; ++m_) {                                               \
    const int r_ = wr * 64 + m_ * 16 + l15;                                      \
    _Pragma("unroll")                                                            \
    for (int kk_ = 0; kk_ < 2; ++kk_)                                            \
      DST[m_][kk_] = *(const bf16x8*)((const char*)&As[buf][0] + r_ * 128 +      \
                                      ((kk_ * 64 + aColB) ^ aXor));              \
  }
#define LDBn(buf, DST, nb)                                                       \
  _Pragma("unroll")                                                              \
  for (int n_ = 0; n_ < 2; ++n_) {                                               \
    const int r_ = wc * 64 + ((nb) + n_) * 16 + l15;                             \
    _Pragma("unroll")                                                            \
    for (int kk_ = 0; kk_ < 2; ++kk_)                                            \
      DST[n_][kk_] = *(const bf16x8*)((const char*)&Bs[buf][0] + r_ * 128 +      \
                                      ((kk_ * 64 + aColB) ^ aXor));              \
  }
#define MMAQ(AF, BF, nb)                                                         \
  _Pragma("unroll")                                                              \
  for (int m_ = 0; m_ < 4; ++m_)                                                 \
    _Pragma("unroll")                                                            \
    for (int n_ = 0; n_ < 2; ++n_)                                               \
      _Pragma("unroll")                                                          \
      for (int kk_ = 0; kk_ < 2; ++kk_)                                          \
        acc[m_][(nb) + n_] = __builtin_amdgcn_mfma_f32_16x16x32_bf16(            \
            AF[m_][kk_], BF[n_][kk_], acc[m_][(nb) + n_], 0, 0, 0);

  // One K-tile, two phases. AFc = this tile's A regs, AFn = next tile's.
  // P0: read bfHi(cur) [4]; stage A(kt+2); lgkm(4); MMA half0 (bfLo, read last phase)
  // P1: read A(cur^1)+bfLo(cur^1) [12]; stage B(kt+2); lgkm(12); MMA half1 (bfHi)
#define TILE(kt, AFc, AFn, cur)                                                  \
  do {                                                                           \
    const bool preA = (kt) + 2 < nk;                                             \
    const bool nxt  = (kt) + 1 < nk;                                             \
    __builtin_amdgcn_s_barrier();                                                \
    LDBn(cur, bfHi, 2);                                                          \
    if (preA) STG_A(cur, (kt) + 2);                                              \
    asm volatile("s_waitcnt lgkmcnt(4)" ::: "memory");                           \
    __builtin_amdgcn_sched_barrier(0);                                           \
    __builtin_amdgcn_s_setprio(1);                                               \
    MMAQ(AFc, bfLo, 0);                                                          \
    __builtin_amdgcn_s_setprio(0);                                               \
    __builtin_amdgcn_sched_barrier(0);                                           \
    if (preA)      { asm volatile("s_waitcnt vmcnt(4)" ::: "memory"); }          \
    else if (nxt)  { asm volatile("s_waitcnt vmcnt(0)" ::: "memory"); }          \
    __builtin_amdgcn_s_barrier();                                                \
    if (nxt) { LDA(cur ^ 1, AFn); LDBn(cur ^ 1, bfLo, 0); }                      \
    if (preA) STG_B(cur, (kt) + 2);                                              \
    if (nxt) { asm volatile("s_waitcnt lgkmcnt(12)" ::: "memory"); }             \
    else     { asm volatile("s_waitcnt lgkmcnt(0)"  ::: "memory"); }             \
    __builtin_amdgcn_sched_barrier(0);                                           \
    __builtin_amdgcn_s_setprio(1);                                               \
    MMAQ(AFc, bfHi, 2);                                                          \
    __builtin_amdgcn_s_setprio(0);                                               \
    __builtin_amdgcn_sched_barrier(0);                                           \
  } while (0)

  // prologue: prime tiles 0,1 (A then B per tile); wait tile 0; initial reads
  STG_A(0, 0); STG_B(0, 0);
  STG_A(1, 1); STG_B(1, 1);
  asm volatile("s_waitcnt vmcnt(6)" ::: "memory");
  __builtin_amdgcn_s_barrier();
  LDA(0, afS0); LDBn(0, bfLo, 0);   // 12 reads in flight into kt=0 P0

  for (int kt = 0; kt < nk; kt += 2) {
    TILE(kt,     afS0, afS1, 0);
    TILE(kt + 1, afS1, afS0, 1);
  }
#undef STG
#undef STG_A
#undef STG_B
#undef LDA
#undef LDBn
#undef MMAQ
#undef TILE

#pragma unroll
  for (int m = 0; m < 4; ++m) {
#pragma unroll
    for (int n = 0; n < 4; ++n) {
#pragma unroll
      for (int r = 0; r < 4; ++r) {
        const int row = rowBase + wr * 64 + m * 16 + l4 * 4 + r;
        const int col = colBase + wc * 64 + n * 16 + l15;
        float v = acc[m][n][r] + bias[col];
        if (EPI == 0) {
          const int h = col / 384;
          const int sub = col - h * 384;
          const int t = sub >> 7, hd = sub & 127;
          const int bb = row >> 11, s = row & 2047;
          const size_t bh = (size_t)bb * NH + h;
          if (t == 0)      Qb[(bh * NS + s) * NHD + hd] = f2bf(v * 0.08838834764831845f);
          else if (t == 1) Kb[(bh * NS + s) * NHD + hd] = f2bf(v);
          else             Vtb[(bh * NHD + hd) * NS + s] = f2bf(v);
        } else {
          const size_t idx = (size_t)row * N + col;
          out[idx] = v + residual[idx];
        }
      }
    }
  }
}

// ---------------- flash attention v4: QBLK=32/wave, K in LDS (swizzled) ----------------
__global__ __launch_bounds__(256, 2) void attn_kernel(
    const short* __restrict__ Qb, const short* __restrict__ Kb,
    const short* __restrict__ Vtb, const float* __restrict__ alibi,
    const int* __restrict__ amask, short* __restrict__ Ob) {
  const int tid = threadIdx.x;
  const int w = tid >> 6, l = tid & 63;
  const int l15 = l & 15, l4 = l >> 4;
  const int flat = blockIdx.x;
  const int bh = flat & 31;
  const int y = (flat >> 5) & 7, z = flat >> 8;
  const int qt = z ? (15 - y) : y;
  const int bb = bh >> 4, h = bh & 15;
  const int q0 = qt * 128;
  const int qw = q0 + w * 32;
  const int NT = 2 * qt + 2;

  __shared__ float biasLds[NS];
  __shared__ short Ks[2][64 * 128];
  __shared__ short Plds[4][32 * 64];

  {
    const float* abase = alibi + (size_t)bh * NS;
    const int* mbase = amask + (size_t)bb * NS;
    for (int i = tid; i < NS; i += 256)
      biasLds[i] = mbase[i] ? abase[i] : -1e30f;
  }

  const short* kbase = Kb + (size_t)bh * NS * NHD;
  const short* vbase = Vtb + (size_t)bh * NHD * NS;

#define KSTAGE(buf, kt0) do {                                                  \
    _Pragma("unroll")                                                          \
    for (int i_ = 0; i_ < 4; ++i_) {                                           \
      const int Lb_ = w * 4096 + i_ * 1024 + l * 16;                           \
      const int row_ = Lb_ >> 8;                                               \
      const int X_ = (Lb_ & 255) ^ ((row_ & 7) << 4);                          \
      gl_lds16((const short*)((const char*)kbase + (size_t)((kt0) * 64 + row_) * 256 + X_), \
               (short*)((char*)&Ks[buf][0] + (w * 4096 + i_ * 1024)));         \
    }                                                                          \
  } while (0)

  const short* qp = Qb + ((size_t)bh * NS + qw + l15) * NHD + l4 * 8;
  bf16x8 qf[2][4];
#pragma unroll
  for (int c = 0; c < 2; ++c)
#pragma unroll
    for (int s = 0; s < 4; ++s)
      qf[c][s] = *(const bf16x8*)(qp + c * 16 * NHD + s * 32);

  f32x4 acc[2][8] = {};
  float mrun[2] = {-1e30f, -1e30f}, lrun[2] = {0.f, 0.f};

  short* myP = &Plds[w][0];
  const int pswzB = (l15 & 7) << 4;
  const int qg0 = qw + l15, qg1 = qw + 16 + l15;

  KSTAGE(0, 0);
  __syncthreads();
  int cur = 0;

  for (int t = 0; t < NT; ++t) {
    const int k0 = t << 6;
    if (t + 1 < NT) KSTAGE(cur ^ 1, t + 1);

    if (k0 <= qw + 31) {
      f32x4 sT[2][4] = {};
      __builtin_amdgcn_s_setprio(1);
#pragma unroll
      for (int p = 0; p < 4; ++p) {
        const int lrow = p * 16 + l15;
#pragma unroll
        for (int s = 0; s < 4; ++s) {
          const int lbyte = (lrow << 8) + ((s * 64 + l4 * 16) ^ ((lrow & 7) << 4));
          const bf16x8 kf = *(const bf16x8*)((const char*)&Ks[cur][0] + lbyte);
          sT[0][p] = __builtin_amdgcn_mfma_f32_16x16x32_bf16(kf, qf[0][s], sT[0][p], 0, 0, 0);
          sT[1][p] = __builtin_amdgcn_mfma_f32_16x16x32_bf16(kf, qf[1][s], sT[1][p], 0, 0, 0);
        }
      }
      __builtin_amdgcn_s_setprio(0);

      const short* vp = vbase + (size_t)l15 * NS + k0 + l4 * 8;
      bf16x8 vA[8];
#pragma unroll
      for (int t8 = 0; t8 < 8; ++t8)
        vA[t8] = *(const bf16x8*)(vp + (size_t)t8 * 16 * NS);

      const bool full = (k0 + 63 <= qw);
      float pv[2][16];
      float tmax[2] = {-1e30f, -1e30f};
#pragma unroll
      for (int p = 0; p < 4; ++p) {
        const f32x4 bvec = *(const f32x4*)&biasLds[k0 + p * 16 + l4 * 4];
#pragma unroll
        for (int r = 0; r < 4; ++r) {
          const int kg = k0 + p * 16 + l4 * 4 + r;
          float v0 = sT[0][p][r] + bvec[r];
          float v1 = sT[1][p][r] + bvec[r];
          if (!full) {
            v0 = (kg <= qg0) ? v0 : -1e30f;
            v1 = (kg <= qg1) ? v1 : -1e30f;
          }
          pv[0][p * 4 + r] = v0; pv[1][p * 4 + r] = v1;
          tmax[0] = fmaxf(tmax[0], v0);
          tmax[1] = fmaxf(tmax[1], v1);
        }
      }
      float alpha[2];
#pragma unroll
      for (int c = 0; c < 2; ++c) {
        tmax[c] = fmaxf(tmax[c], __shfl_xor(tmax[c], 16, 64));
        tmax[c] = fmaxf(tmax[c], __shfl_xor(tmax[c], 32, 64));
        const float mnew = fmaxf(mrun[c], tmax[c]);
        alpha[c] = __expf(mrun[c] - mnew);
        mrun[c] = mnew;
        float psum = 0.f;
#pragma unroll
        for (int i = 0; i < 16; ++i) {
          pv[c][i] = __expf(pv[c][i] - mnew);
          psum += pv[c][i];
        }
        psum += __shfl_xor(psum, 16, 64);
        psum += __shfl_xor(psum, 32, 64);
        lrun[c] = lrun[c] * alpha[c] + psum;
#pragma unroll
        for (int t8 = 0; t8 < 8; ++t8)
#pragma unroll
          for (int r = 0; r < 4; ++r)
            acc[c][t8][r] *= alpha[c];
      }

#pragma unroll
      for (int c = 0; c < 2; ++c)
#pragma unroll
        for (int p = 0; p < 4; ++p) {
          bf16x4 pk = { (__bf16)pv[c][p * 4 + 0], (__bf16)pv[c][p * 4 + 1],
                        (__bf16)pv[c][p * 4 + 2], (__bf16)pv[c][p * 4 + 3] };
          const int byteoff = ((16 * c + l15) << 7) + (((p * 16 + l4 * 4) << 1) ^ pswzB);
          *(bf16x4*)((char*)myP + byteoff) = pk;
        }
      asm volatile("s_waitcnt lgkmcnt(0)" ::: "memory");

      bf16x8 pfA[2], pfB[2];
#pragma unroll
      for (int c = 0; c < 2; ++c)
        pfA[c] = *(const bf16x8*)((const char*)myP + ((16 * c + l15) << 7) + ((l4 * 16) ^ pswzB));
      bf16x8 vB[8];
#pragma unroll
      for (int t8 = 0; t8 < 8; ++t8)
        vB[t8] = *(const bf16x8*)(vp + 32 + (size_t)t8 * 16 * NS);
      __builtin_amdgcn_s_setprio(1);
#pragma unroll
      for (int t8 = 0; t8 < 8; ++t8) {
        acc[0][t8] = __builtin_amdgcn_mfma_f32_16x16x32_bf16(vA[t8], pfA[0], acc[0][t8], 0, 0, 0);
        acc[1][t8] = __builtin_amdgcn_mfma_f32_16x16x32_bf16(vA[t8], pfA[1], acc[1][t8], 0, 0, 0);
      }
      __builtin_amdgcn_s_setprio(0);
#pragma unroll
      for (int c = 0; c < 2; ++c)
        pfB[c] = *(const bf16x8*)((const char*)myP + ((16 * c + l15) << 7) + ((64 + l4 * 16) ^ pswzB));
      __builtin_amdgcn_s_setprio(1);
#pragma unroll
      for (int t8 = 0; t8 < 8; ++t8) {
        acc[0][t8] = __builtin_amdgcn_mfma_f32_16x16x32_bf16(vB[t8], pfB[0], acc[0][t8], 0, 0, 0);
        acc[1][t8] = __builtin_amdgcn_mfma_f32_16x16x32_bf16(vB[t8], pfB[1], acc[1][t8], 0, 0, 0);
      }
      __builtin_amdgcn_s_setprio(0);
    }

    __syncthreads();
    cur ^= 1;
  }
#undef KSTAGE

#pragma unroll
  for (int c = 0; c < 2; ++c) {
    const float inv = (lrun[c] > 0.f) ? 1.0f / lrun[c] : 0.f;
    short* obase = Ob + ((size_t)bb * NS + qw + 16 * c + l15) * ND + h * NHD + l4 * 4;
#pragma unroll
    for (int t8 = 0; t8 < 8; ++t8) {
      bf16x4 o = { (__bf16)(acc[c][t8][0] * inv), (__bf16)(acc[c][t8][1] * inv),
                   (__bf16)(acc[c][t8][2] * inv), (__bf16)(acc[c][t8][3] * inv) };
      *(bf16x4*)&obase[t8 * 16] = o;
    }
  }
}

extern "C" void kernel_launch(void* const* d_in, const int* in_sizes, int n_in,
                              void* d_out, int out_size, void* d_ws, size_t ws_size,
                              hipStream_t stream) {
  const float* hidden   = (const float*)d_in[0];
  const float* residual = (const float*)d_in[1];
  const float* alibi    = (const float*)d_in[2];
  const float* W_qkv    = (const float*)d_in[3];
  const float* b_qkv    = (const float*)d_in[4];
  const float* W_o      = (const float*)d_in[5];
  const float* b_o      = (const float*)d_in[6];
  const int*   amask    = (const int*)d_in[7];
  float* out = (float*)d_out;

  char* p = (char*)d_ws;
  short* Abuf  = (short*)p; p += (size_t)NM * ND * 2;
  short* WqkvT = (short*)p; p += (size_t)NQKV * ND * 2;
  short* WoT   = (short*)p; p += (size_t)ND * ND * 2;
  short* Qb    = (short*)p; p += (size_t)NB * NH * NS * NHD * 2;
  short* Kb    = (short*)p; p += (size_t)NB * NH * NS * NHD * 2;
  short* Vtb   = (short*)p; p += (size_t)NB * NH * NS * NHD * 2;
  short* Ob    = (short*)p; p += (size_t)NM * ND * 2;

  cvt_bf16_kernel<<<(NM * ND / 4) / 256, 256, 0, stream>>>(hidden, Abuf, NM * ND / 4);
  transpose_cvt_kernel<<<dim3(NQKV / 64, ND / 64), dim3(64, 4), 0, stream>>>(W_qkv, WqkvT, ND, NQKV);
  transpose_cvt_kernel<<<dim3(ND / 64, ND / 64), dim3(64, 4), 0, stream>>>(W_o, WoT, ND, ND);
  gemm_kernel<0><<<dim3((NQKV / 128) * (NM / 256)), 512, 0, stream>>>(
      Abuf, WqkvT, ND, NQKV, NQKV / 128, b_qkv, Qb, Kb, Vtb, nullptr, nullptr);
  attn_kernel<<<dim3(512), 256, 0, stream>>>(Qb, Kb, Vtb, alibi, amask, Ob);
  gemm_kernel<1><<<dim3((ND / 128) * (NM / 256)), 512, 0, stream>>>(
      Ob, WoT, ND, ND, ND / 128, b_o, nullptr, nullptr, nullptr, residual, out);
}